// Round 3
// baseline (107.053 us; speedup 1.0000x reference)
//
#include <hip/hip_runtime.h>
#include <hip/hip_bf16.h>

// ---- problem constants ----
#define BATCH   4096
#define FEAT    1024
#define NTREES  10
#define NNODES  255
#define NLEAF   256
#define NCLS    1000
#define KTOT    (NTREES*NLEAF) // 2560 = GEMM2 K

typedef __attribute__((ext_vector_type(8))) short  bf16x8;
typedef __attribute__((ext_vector_type(4))) float  f32x4;

// workspace layout (bytes)
#define OFF_XB 0u
#define OFF_WT 8388608u
#define OFF_PT 13631488u
#define OFF_RT 18874368u

#define WAITVM(N) asm volatile("s_waitcnt vmcnt(" #N ")" ::: "memory")
#define WAITLGKM() asm volatile("s_waitcnt lgkmcnt(0)" ::: "memory")
#define BAR() __builtin_amdgcn_s_barrier()

__device__ __forceinline__ void load_lds16(const void* g, void* l) {
    __builtin_amdgcn_global_load_lds(
        (const __attribute__((address_space(1))) unsigned int*)g,
        (__attribute__((address_space(3))) unsigned int*)l, 16, 0, 0);
}

// ---------------- conversion kernels (unchanged) ----------------

__global__ void k_cvt_x(const float* __restrict__ x, __hip_bfloat16* __restrict__ xb) {
    int i = blockIdx.x * 256 + threadIdx.x;
    float4 v = reinterpret_cast<const float4*>(x)[i];
    union { ushort4 u; __hip_bfloat16 h[4]; } o;
    o.h[0] = __float2bfloat16(v.x);
    o.h[1] = __float2bfloat16(v.y);
    o.h[2] = __float2bfloat16(v.z);
    o.h[3] = __float2bfloat16(v.w);
    reinterpret_cast<ushort4*>(xb)[i] = o.u;
}

__global__ void k_cvt_w(const float* __restrict__ w, __hip_bfloat16* __restrict__ wT) {
    __shared__ float tile[32][33];
    int t  = blockIdx.z;
    int nb = blockIdx.x * 32;
    int fb = blockIdx.y * 32;
    int tx = threadIdx.x & 31, ty = threadIdx.x >> 5;
#pragma unroll
    for (int j = 0; j < 4; ++j) {
        int f = fb + ty + j * 8;
        int n = nb + tx;
        float v = (n < NNODES) ? w[((size_t)t * FEAT + f) * NNODES + n] : 0.f;
        tile[ty + j * 8][tx] = v;
    }
    __syncthreads();
#pragma unroll
    for (int j = 0; j < 4; ++j) {
        int n = nb + ty + j * 8;
        int f = fb + tx;
        wT[((size_t)t * NLEAF + n) * FEAT + f] = __float2bfloat16(tile[tx][ty + j * 8]);
    }
}

__global__ void k_cvt_p(const float* __restrict__ p, __hip_bfloat16* __restrict__ pT) {
    __shared__ float tile[32][33];
    int cb = blockIdx.x * 32;
    int kb = blockIdx.y * 32;
    int tx = threadIdx.x & 31, ty = threadIdx.x >> 5;
#pragma unroll
    for (int j = 0; j < 4; ++j) {
        int k = kb + ty + j * 8;
        int c = cb + tx;
        float v = (c < NCLS) ? p[(size_t)k * NCLS + c] * 0.1f : 0.f;
        tile[ty + j * 8][tx] = v;
    }
    __syncthreads();
#pragma unroll
    for (int j = 0; j < 4; ++j) {
        int c = cb + ty + j * 8;
        int k = kb + tx;
        pT[(size_t)c * KTOT + k] = __float2bfloat16(tile[tx][ty + j * 8]);
    }
}

// ---------------- GEMM1 + sigmoid + routing ----------------
// tile 128(M) x 256(N=one tree), BK=64, 512 thr = 8 waves (2M x 4N), wave 64x64
// 3-buffer LDS ring (3 x 48KB = 144KB), counted vmcnt 2 tiles deep.
__global__ __launch_bounds__(512, 2) void k_gemm1_route(
        const __hip_bfloat16* __restrict__ xb,
        const __hip_bfloat16* __restrict__ wT,
        __hip_bfloat16* __restrict__ route) {
    __shared__ __align__(16) char smem[147456];   // 3 x (A 16KB + B 32KB); epilogue Ds 131.6KB

    // XCD-chunked swizzle: 320 blocks = 8 XCD x 40
    int wg = blockIdx.y * 32 + blockIdx.x;
    int sw = (wg & 7) * 40 + (wg >> 3);
    const int bm = sw & 31;          // 32 M-tiles
    const int tr = sw >> 5;          // 10 trees

    const int tid = threadIdx.x;
    const int lane = tid & 63, wid = tid >> 6;
    const int wm = wid >> 2, wn = wid & 3;        // 2 x 4 waves, wave 64x64
    const int r8 = lane >> 3, c8 = lane & 7;

    f32x4 acc[4][4] = {};

    const __hip_bfloat16* Ag = xb + (size_t)(bm * 128) * FEAT;
    const __hip_bfloat16* Bg = wT + (size_t)tr * NLEAF * FEAT;

    const int NT = FEAT / 64;                     // 16

    auto stage = [&](int t) {
        const int k0 = t * 64;
        char* base = smem + (t % 3) * 49152;
        // A: 128x64 = 16KB -> 2 loads/wave
#pragma unroll
        for (int q = 0; q < 2; ++q) {
            int row = (wid * 2 + q) * 8 + r8;
            load_lds16(Ag + (size_t)row * FEAT + k0 + ((c8 ^ r8) << 3),
                       base + (wid * 2 + q) * 1024);
        }
        // B: 256x64 = 32KB -> 4 loads/wave
#pragma unroll
        for (int q = 0; q < 4; ++q) {
            int row = (wid * 4 + q) * 8 + r8;
            load_lds16(Bg + (size_t)row * FEAT + k0 + ((c8 ^ r8) << 3),
                       base + 16384 + (wid * 4 + q) * 1024);
        }
    };

    stage(0);
    stage(1);                                     // 12 loads in flight

    for (int t = 0; t < NT; ++t) {
        if (t + 2 < NT) { stage(t + 2); WAITVM(12); }
        else if (t + 1 < NT) { WAITVM(6); }
        else { WAITVM(0); }
        BAR();                                    // tile t fully staged (all waves)

        const char* As = smem + (t % 3) * 49152;
        const char* Bs = As + 16384;
#pragma unroll
        for (int ks = 0; ks < 2; ++ks) {
            const int s = ks * 4 + (lane >> 4);
            const int x7 = lane & 7;
            bf16x8 a[4], b[4];
#pragma unroll
            for (int mf = 0; mf < 4; ++mf) {
                int row = wm * 64 + mf * 16 + (lane & 15);
                a[mf] = *(const bf16x8*)(As + row * 128 + ((s ^ x7) << 4));
            }
#pragma unroll
            for (int nf = 0; nf < 4; ++nf) {
                int row = wn * 64 + nf * 16 + (lane & 15);
                b[nf] = *(const bf16x8*)(Bs + row * 128 + ((s ^ x7) << 4));
            }
            __builtin_amdgcn_s_setprio(1);
#pragma unroll
            for (int mf = 0; mf < 4; ++mf)
#pragma unroll
                for (int nf = 0; nf < 4; ++nf)
                    acc[mf][nf] = __builtin_amdgcn_mfma_f32_16x16x32_bf16(
                        a[mf], b[nf], acc[mf][nf], 0, 0, 0);
            __builtin_amdgcn_s_setprio(0);
        }
        WAITLGKM();                               // my ds_reads retired
        BAR();                                    // safe for next iter's stage
    }

    // ---- epilogue: sigmoid -> Ds[128][257] fp32 -> routing -> route bf16 ----
    float* Ds = (float*)smem;
#pragma unroll
    for (int mf = 0; mf < 4; ++mf)
#pragma unroll
        for (int nf = 0; nf < 4; ++nf)
#pragma unroll
            for (int r = 0; r < 4; ++r) {
                int row = wm * 64 + mf * 16 + (lane >> 4) * 4 + r;
                int col = wn * 64 + nf * 16 + (lane & 15);
                float z = acc[mf][nf][r];
                Ds[row * 257 + col] = 1.f / (1.f + __expf(-z));
            }
    __syncthreads();
#pragma unroll
    for (int rr = 0; rr < 16; ++rr) {
        int row = wid * 16 + rr;                  // 0..127
#pragma unroll
        for (int cc = 0; cc < 4; ++cc) {
            int leaf = cc * 64 + lane;
            float prod = 1.f;
#pragma unroll
            for (int l = 0; l < 8; ++l) {
                int nidx = (1 << l) - 1 + (leaf >> (8 - l));
                float v = Ds[row * 257 + nidx];
                prod *= (((leaf >> (7 - l)) & 1) == 0) ? v : (1.f - v);
            }
            int bb = bm * 128 + row;
            route[(size_t)bb * KTOT + tr * NLEAF + leaf] = __float2bfloat16(prod);
        }
    }
}

// ---------------- GEMM2 + clip ----------------
// tile 128x128, K=2560, BK=64; 256 thr = 4 waves (2M x 2N), wave 64x64
// 4-buffer LDS ring (4 x 32KB = 128KB), counted vmcnt 3 tiles deep. Grid 256 = 1/CU.
__global__ __launch_bounds__(256) void k_gemm2(
        const __hip_bfloat16* __restrict__ route,
        const __hip_bfloat16* __restrict__ pT,
        float* __restrict__ out) {
    __shared__ __align__(16) char smem[131072];

    int wg = blockIdx.y * 32 + blockIdx.x;        // 256 blocks
    int sw = (wg & 7) * 32 + (wg >> 3);           // 8 XCD x 32
    const int bm = sw & 31;                       // 32 M-tiles
    const int bn = sw >> 5;                       // 8 N-tiles (same bn per XCD chunk)

    const int tid = threadIdx.x;
    const int lane = tid & 63, wid = tid >> 6;
    const int wm = wid >> 1, wn = wid & 1;        // 2 x 2 waves, wave 64x64
    const int r8 = lane >> 3, c8 = lane & 7;

    f32x4 acc[4][4] = {};

    const __hip_bfloat16* Ag = route + (size_t)(bm * 128) * KTOT;
    const __hip_bfloat16* Bg = pT + (size_t)(bn * 128) * KTOT;

    const int NT = KTOT / 64;                     // 40

    auto stage = [&](int t) {
        const int k0 = t * 64;
        char* base = smem + (t & 3) * 32768;
        // A: 128x64 = 16KB -> 4 loads/wave
#pragma unroll
        for (int q = 0; q < 4; ++q) {
            int row = (wid * 4 + q) * 8 + r8;
            load_lds16(Ag + (size_t)row * KTOT + k0 + ((c8 ^ r8) << 3),
                       base + (wid * 4 + q) * 1024);
        }
        // B: 128x64 = 16KB -> 4 loads/wave
#pragma unroll
        for (int q = 0; q < 4; ++q) {
            int row = (wid * 4 + q) * 8 + r8;
            load_lds16(Bg + (size_t)row * KTOT + k0 + ((c8 ^ r8) << 3),
                       base + 16384 + (wid * 4 + q) * 1024);
        }
    };

    stage(0);
    stage(1);
    stage(2);                                     // 24 loads in flight

    for (int t = 0; t < NT; ++t) {
        if (t + 3 < NT) { stage(t + 3); WAITVM(24); }
        else if (t + 2 < NT) { WAITVM(16); }
        else if (t + 1 < NT) { WAITVM(8); }
        else { WAITVM(0); }
        BAR();

        const char* As = smem + (t & 3) * 32768;
        const char* Bs = As + 16384;
#pragma unroll
        for (int ks = 0; ks < 2; ++ks) {
            const int s = ks * 4 + (lane >> 4);
            const int x7 = lane & 7;
            bf16x8 a[4], b[4];
#pragma unroll
            for (int mf = 0; mf < 4; ++mf) {
                int row = wm * 64 + mf * 16 + (lane & 15);
                a[mf] = *(const bf16x8*)(As + row * 128 + ((s ^ x7) << 4));
            }
#pragma unroll
            for (int nf = 0; nf < 4; ++nf) {
                int row = wn * 64 + nf * 16 + (lane & 15);
                b[nf] = *(const bf16x8*)(Bs + row * 128 + ((s ^ x7) << 4));
            }
            __builtin_amdgcn_s_setprio(1);
#pragma unroll
            for (int mf = 0; mf < 4; ++mf)
#pragma unroll
                for (int nf = 0; nf < 4; ++nf)
                    acc[mf][nf] = __builtin_amdgcn_mfma_f32_16x16x32_bf16(
                        a[mf], b[nf], acc[mf][nf], 0, 0, 0);
            __builtin_amdgcn_s_setprio(0);
        }
        WAITLGKM();
        BAR();
    }

    // clip + masked store (output is 1000 wide)
#pragma unroll
    for (int mf = 0; mf < 4; ++mf)
#pragma unroll
        for (int nf = 0; nf < 4; ++nf)
#pragma unroll
            for (int r = 0; r < 4; ++r) {
                int row = bm * 128 + wm * 64 + mf * 16 + (lane >> 4) * 4 + r;
                int col = bn * 128 + wn * 64 + nf * 16 + (lane & 15);
                if (col < NCLS) {
                    float v = acc[mf][nf][r];
                    v = fminf(fmaxf(v, 0.f), 1.f);
                    out[(size_t)row * NCLS + col] = v;
                }
            }
}

extern "C" void kernel_launch(void* const* d_in, const int* in_sizes, int n_in,
                              void* d_out, int out_size, void* d_ws, size_t ws_size,
                              hipStream_t stream) {
    const float* x = (const float*)d_in[0];
    const float* w = (const float*)d_in[1];
    const float* p = (const float*)d_in[2];
    float* out = (float*)d_out;
    char* ws = (char*)d_ws;

    __hip_bfloat16* xb    = (__hip_bfloat16*)(ws + OFF_XB);
    __hip_bfloat16* wT    = (__hip_bfloat16*)(ws + OFF_WT);
    __hip_bfloat16* pT    = (__hip_bfloat16*)(ws + OFF_PT);
    __hip_bfloat16* route = (__hip_bfloat16*)(ws + OFF_RT);

    k_cvt_x<<<4096, 256, 0, stream>>>(x, xb);
    k_cvt_w<<<dim3(8, 32, 10), 256, 0, stream>>>(w, wT);
    k_cvt_p<<<dim3(32, 80), 256, 0, stream>>>(p, pT);
    k_gemm1_route<<<dim3(32, 10), 512, 0, stream>>>(xb, wT, route);
    k_gemm2<<<dim3(32, 8), 256, 0, stream>>>(route, pT, out);
}

// Round 4
// 90.431 us; speedup vs baseline: 1.1838x; 1.1838x over previous
//
#include <hip/hip_runtime.h>
#include <hip/hip_bf16.h>

// ---- problem constants ----
#define BATCH   4096
#define FEAT    1024
#define NTREES  10
#define NNODES  255
#define NLEAF   256
#define NCLS    1000
#define KTOT    (NTREES*NLEAF) // 2560 = GEMM2 K

typedef __attribute__((ext_vector_type(8))) short  bf16x8;
typedef __attribute__((ext_vector_type(4))) float  f32x4;

// workspace layout (bytes)
#define OFF_XB 0u
#define OFF_WT 8388608u
#define OFF_PT 13631488u
#define OFF_RT 18874368u

#define WAITVM(N) asm volatile("s_waitcnt vmcnt(" #N ")" ::: "memory")
#define WAITLGKM() asm volatile("s_waitcnt lgkmcnt(0)" ::: "memory")
#define BAR() __builtin_amdgcn_s_barrier()

__device__ __forceinline__ void load_lds16(const void* g, void* l) {
    __builtin_amdgcn_global_load_lds(
        (const __attribute__((address_space(1))) unsigned int*)g,
        (__attribute__((address_space(3))) unsigned int*)l, 16, 0, 0);
}

// ---------------- conversion kernels (unchanged) ----------------

__global__ void k_cvt_x(const float* __restrict__ x, __hip_bfloat16* __restrict__ xb) {
    int i = blockIdx.x * 256 + threadIdx.x;
    float4 v = reinterpret_cast<const float4*>(x)[i];
    union { ushort4 u; __hip_bfloat16 h[4]; } o;
    o.h[0] = __float2bfloat16(v.x);
    o.h[1] = __float2bfloat16(v.y);
    o.h[2] = __float2bfloat16(v.z);
    o.h[3] = __float2bfloat16(v.w);
    reinterpret_cast<ushort4*>(xb)[i] = o.u;
}

__global__ void k_cvt_w(const float* __restrict__ w, __hip_bfloat16* __restrict__ wT) {
    __shared__ float tile[32][33];
    int t  = blockIdx.z;
    int nb = blockIdx.x * 32;
    int fb = blockIdx.y * 32;
    int tx = threadIdx.x & 31, ty = threadIdx.x >> 5;
#pragma unroll
    for (int j = 0; j < 4; ++j) {
        int f = fb + ty + j * 8;
        int n = nb + tx;
        float v = (n < NNODES) ? w[((size_t)t * FEAT + f) * NNODES + n] : 0.f;
        tile[ty + j * 8][tx] = v;
    }
    __syncthreads();
#pragma unroll
    for (int j = 0; j < 4; ++j) {
        int n = nb + ty + j * 8;
        int f = fb + tx;
        wT[((size_t)t * NLEAF + n) * FEAT + f] = __float2bfloat16(tile[tx][ty + j * 8]);
    }
}

__global__ void k_cvt_p(const float* __restrict__ p, __hip_bfloat16* __restrict__ pT) {
    __shared__ float tile[32][33];
    int cb = blockIdx.x * 32;
    int kb = blockIdx.y * 32;
    int tx = threadIdx.x & 31, ty = threadIdx.x >> 5;
#pragma unroll
    for (int j = 0; j < 4; ++j) {
        int k = kb + ty + j * 8;
        int c = cb + tx;
        float v = (c < NCLS) ? p[(size_t)k * NCLS + c] * 0.1f : 0.f;
        tile[ty + j * 8][tx] = v;
    }
    __syncthreads();
#pragma unroll
    for (int j = 0; j < 4; ++j) {
        int c = cb + ty + j * 8;
        int k = kb + tx;
        pT[(size_t)c * KTOT + k] = __float2bfloat16(tile[tx][ty + j * 8]);
    }
}

// ---------------- GEMM1 + sigmoid + routing ----------------
// tile 64(M) x 256(N=one tree), BK=64, 512 thr = 8 waves (2M x 4N), wave 32x64
// dbuf 80KB, 2-phase/K-tile split: {ds_reads || early stage issue -> lgkm0 -> MFMA}
__global__ __launch_bounds__(512, 4) void k_gemm1_route(
        const __hip_bfloat16* __restrict__ xb,
        const __hip_bfloat16* __restrict__ wT,
        __hip_bfloat16* __restrict__ route) {
    __shared__ __align__(16) char smem[81920];

    int wg = blockIdx.y * 64 + blockIdx.x;          // 640 blocks
    int sw = (wg & 7) * 80 + (wg >> 3);             // 8 XCD x 80 (B-panel L2-resident)
    const int bm = sw & 63;
    const int tr = sw >> 6;

    const int tid = threadIdx.x;
    const int lane = tid & 63, wid = tid >> 6;
    const int wm = wid >> 2, wn = wid & 3;          // 2M x 4N, wave 32x64
    const int r8 = lane >> 3, c8 = lane & 7;

    f32x4 acc[2][4] = {};

    const __hip_bfloat16* Ag = xb + (size_t)(bm * 64) * FEAT;
    const __hip_bfloat16* Bg = wT + (size_t)tr * NLEAF * FEAT;

    const int NT = FEAT / 64;                       // 16

    auto stageA = [&](int t) {
        char* base = smem + (t & 1) * 40960;
        load_lds16(Ag + (size_t)(wid * 8 + r8) * FEAT + t * 64 + ((c8 ^ r8) << 3),
                   base + wid * 1024);
    };
    auto stageB = [&](int t, int q) {
        char* base = smem + (t & 1) * 40960 + 8192;
        int row = (wid * 4 + q) * 8 + r8;
        load_lds16(Bg + (size_t)row * FEAT + t * 64 + ((c8 ^ r8) << 3),
                   base + (wid * 4 + q) * 1024);
    };

    stageA(0); stageB(0, 0); stageB(0, 1); stageB(0, 2); stageB(0, 3);

    for (int t = 0; t < NT; ++t) {
        WAITVM(0);                                  // tile t landed (own 5 loads)
        BAR();                                      // all waves' loads landed
        const char* As = smem + (t & 1) * 40960;
        const char* Bs = As + 8192;
        const int x7 = lane & 7;
        const bool pf = (t + 1 < NT);

        // ---- phase 1: ks = 0 ----
        {
            const int s = (lane >> 4);
            bf16x8 a[2], b[4];
#pragma unroll
            for (int mf = 0; mf < 2; ++mf) {
                int row = wm * 32 + mf * 16 + (lane & 15);
                a[mf] = *(const bf16x8*)(As + row * 128 + ((s ^ x7) << 4));
            }
#pragma unroll
            for (int nf = 0; nf < 4; ++nf) {
                int row = wn * 64 + nf * 16 + (lane & 15);
                b[nf] = *(const bf16x8*)(Bs + row * 128 + ((s ^ x7) << 4));
            }
            if (pf) { stageB(t + 1, 0); stageB(t + 1, 1); }
            WAITLGKM();
            __builtin_amdgcn_s_setprio(1);
#pragma unroll
            for (int mf = 0; mf < 2; ++mf)
#pragma unroll
                for (int nf = 0; nf < 4; ++nf)
                    acc[mf][nf] = __builtin_amdgcn_mfma_f32_16x16x32_bf16(
                        a[mf], b[nf], acc[mf][nf], 0, 0, 0);
            __builtin_amdgcn_s_setprio(0);
        }
        // ---- phase 2: ks = 1 ----
        {
            const int s = 4 + (lane >> 4);
            bf16x8 a[2], b[4];
#pragma unroll
            for (int mf = 0; mf < 2; ++mf) {
                int row = wm * 32 + mf * 16 + (lane & 15);
                a[mf] = *(const bf16x8*)(As + row * 128 + ((s ^ x7) << 4));
            }
#pragma unroll
            for (int nf = 0; nf < 4; ++nf) {
                int row = wn * 64 + nf * 16 + (lane & 15);
                b[nf] = *(const bf16x8*)(Bs + row * 128 + ((s ^ x7) << 4));
            }
            if (pf) { stageB(t + 1, 2); stageB(t + 1, 3); stageA(t + 1); }
            WAITLGKM();
            __builtin_amdgcn_s_setprio(1);
#pragma unroll
            for (int mf = 0; mf < 2; ++mf)
#pragma unroll
                for (int nf = 0; nf < 4; ++nf)
                    acc[mf][nf] = __builtin_amdgcn_mfma_f32_16x16x32_bf16(
                        a[mf], b[nf], acc[mf][nf], 0, 0, 0);
            __builtin_amdgcn_s_setprio(0);
        }
    }

    __syncthreads();                                // buffers dead; reuse as Ds

    // ---- epilogue: sigmoid -> Ds[64][257] fp32 -> routing -> route bf16 ----
    float* Ds = (float*)smem;
#pragma unroll
    for (int mf = 0; mf < 2; ++mf)
#pragma unroll
        for (int nf = 0; nf < 4; ++nf)
#pragma unroll
            for (int r = 0; r < 4; ++r) {
                int row = wm * 32 + mf * 16 + (lane >> 4) * 4 + r;
                int col = wn * 64 + nf * 16 + (lane & 15);
                float z = acc[mf][nf][r];
                Ds[row * 257 + col] = 1.f / (1.f + __expf(-z));
            }
    __syncthreads();
#pragma unroll
    for (int rr = 0; rr < 8; ++rr) {
        int row = wid * 8 + rr;                     // 0..63
#pragma unroll
        for (int cc = 0; cc < 4; ++cc) {
            int leaf = cc * 64 + lane;
            float prod = 1.f;
#pragma unroll
            for (int l = 0; l < 8; ++l) {
                int nidx = (1 << l) - 1 + (leaf >> (8 - l));
                float v = Ds[row * 257 + nidx];
                prod *= (((leaf >> (7 - l)) & 1) == 0) ? v : (1.f - v);
            }
            int bb = bm * 64 + row;
            route[(size_t)bb * KTOT + tr * NLEAF + leaf] = __float2bfloat16(prod);
        }
    }
}

// ---------------- GEMM2 + clip ----------------
// tile 128x128, grid 256 (1/CU, no tail), 512 thr = 8 waves:
// K-split-2 (waves 0-3: k<1280, waves 4-7: k>=1280), each half 2x2 of 64x64
// wave tiles, own dbuf (2 x 32KB per half = 128KB), 2-phase split, LDS reduce.
__global__ __launch_bounds__(512, 2) void k_gemm2(
        const __hip_bfloat16* __restrict__ route,
        const __hip_bfloat16* __restrict__ pT,
        float* __restrict__ out) {
    __shared__ __align__(16) char smem[131072];

    int wg = blockIdx.y * 32 + blockIdx.x;          // 256 blocks
    int sw = (wg & 7) * 32 + (wg >> 3);             // 8 XCD x 32
    const int bm = sw >> 3;                         // A(route)-panel L2-resident
    const int bn = sw & 7;                          // pT streams from L3 (5.2MB)

    const int tid = threadIdx.x;
    const int lane = tid & 63, wid = tid >> 6;
    const int h  = wid >> 2;                        // K half
    const int w2 = wid & 3;
    const int wm = w2 >> 1, wn = w2 & 1;            // 64x64 wave tile in 128x128
    const int r8 = lane >> 3, c8 = lane & 7;

    f32x4 acc[4][4] = {};

    const __hip_bfloat16* Ag = route + (size_t)(bm * 128) * KTOT + h * 1280;
    const __hip_bfloat16* Bg = pT + (size_t)(bn * 128) * KTOT + h * 1280;
    char* bufH = smem + h * 65536;

    const int NT = 1280 / 64;                       // 20 per half

    auto stageA = [&](int t, int q) {
        char* base = bufH + (t & 1) * 32768;
        int row = (w2 * 4 + q) * 8 + r8;
        load_lds16(Ag + (size_t)row * KTOT + t * 64 + ((c8 ^ r8) << 3),
                   base + (w2 * 4 + q) * 1024);
    };
    auto stageB = [&](int t, int q) {
        char* base = bufH + (t & 1) * 32768 + 16384;
        int row = (w2 * 4 + q) * 8 + r8;
        load_lds16(Bg + (size_t)row * KTOT + t * 64 + ((c8 ^ r8) << 3),
                   base + (w2 * 4 + q) * 1024);
    };

#pragma unroll
    for (int q = 0; q < 4; ++q) { stageA(0, q); stageB(0, q); }

    for (int t = 0; t < NT; ++t) {
        WAITVM(0);
        BAR();
        const char* As = bufH + (t & 1) * 32768;
        const char* Bs = As + 16384;
        const int x7 = lane & 7;
        const bool pf = (t + 1 < NT);

        // ---- phase 1: ks = 0 ----
        {
            const int s = (lane >> 4);
            bf16x8 a[4], b[4];
#pragma unroll
            for (int f = 0; f < 4; ++f) {
                int ra = wm * 64 + f * 16 + (lane & 15);
                int rb = wn * 64 + f * 16 + (lane & 15);
                a[f] = *(const bf16x8*)(As + ra * 128 + ((s ^ x7) << 4));
                b[f] = *(const bf16x8*)(Bs + rb * 128 + ((s ^ x7) << 4));
            }
            if (pf) { stageA(t + 1, 0); stageA(t + 1, 1); stageB(t + 1, 0); stageB(t + 1, 1); }
            WAITLGKM();
            __builtin_amdgcn_s_setprio(1);
#pragma unroll
            for (int mf = 0; mf < 4; ++mf)
#pragma unroll
                for (int nf = 0; nf < 4; ++nf)
                    acc[mf][nf] = __builtin_amdgcn_mfma_f32_16x16x32_bf16(
                        a[mf], b[nf], acc[mf][nf], 0, 0, 0);
            __builtin_amdgcn_s_setprio(0);
        }
        // ---- phase 2: ks = 1 ----
        {
            const int s = 4 + (lane >> 4);
            bf16x8 a[4], b[4];
#pragma unroll
            for (int f = 0; f < 4; ++f) {
                int ra = wm * 64 + f * 16 + (lane & 15);
                int rb = wn * 64 + f * 16 + (lane & 15);
                a[f] = *(const bf16x8*)(As + ra * 128 + ((s ^ x7) << 4));
                b[f] = *(const bf16x8*)(Bs + rb * 128 + ((s ^ x7) << 4));
            }
            if (pf) { stageA(t + 1, 2); stageA(t + 1, 3); stageB(t + 1, 2); stageB(t + 1, 3); }
            WAITLGKM();
            __builtin_amdgcn_s_setprio(1);
#pragma unroll
            for (int mf = 0; mf < 4; ++mf)
#pragma unroll
                for (int nf = 0; nf < 4; ++nf)
                    acc[mf][nf] = __builtin_amdgcn_mfma_f32_16x16x32_bf16(
                        a[mf], b[nf], acc[mf][nf], 0, 0, 0);
            __builtin_amdgcn_s_setprio(0);
        }
    }

    // ---- cross-half reduce via LDS, then clip + store ----
    __syncthreads();
    float* R = (float*)smem;                        // 4 quads x [64][65] f32
    if (h == 1) {
#pragma unroll
        for (int mf = 0; mf < 4; ++mf)
#pragma unroll
            for (int nf = 0; nf < 4; ++nf)
#pragma unroll
                for (int r = 0; r < 4; ++r) {
                    int row = mf * 16 + (lane >> 4) * 4 + r;
                    int col = nf * 16 + (lane & 15);
                    R[w2 * 4160 + row * 65 + col] = acc[mf][nf][r];
                }
    }
    __syncthreads();
    if (h == 0) {
#pragma unroll
        for (int mf = 0; mf < 4; ++mf)
#pragma unroll
            for (int nf = 0; nf < 4; ++nf)
#pragma unroll
                for (int r = 0; r < 4; ++r) {
                    int row = mf * 16 + (lane >> 4) * 4 + r;
                    int col = nf * 16 + (lane & 15);
                    float v = acc[mf][nf][r] + R[w2 * 4160 + row * 65 + col];
                    v = fminf(fmaxf(v, 0.f), 1.f);
                    int grow = bm * 128 + wm * 64 + row;
                    int gcol = bn * 128 + wn * 64 + col;
                    if (gcol < NCLS)
                        out[(size_t)grow * NCLS + gcol] = v;
                }
    }
}

extern "C" void kernel_launch(void* const* d_in, const int* in_sizes, int n_in,
                              void* d_out, int out_size, void* d_ws, size_t ws_size,
                              hipStream_t stream) {
    const float* x = (const float*)d_in[0];
    const float* w = (const float*)d_in[1];
    const float* p = (const float*)d_in[2];
    float* out = (float*)d_out;
    char* ws = (char*)d_ws;

    __hip_bfloat16* xb    = (__hip_bfloat16*)(ws + OFF_XB);
    __hip_bfloat16* wT    = (__hip_bfloat16*)(ws + OFF_WT);
    __hip_bfloat16* pT    = (__hip_bfloat16*)(ws + OFF_PT);
    __hip_bfloat16* route = (__hip_bfloat16*)(ws + OFF_RT);

    k_cvt_x<<<4096, 256, 0, stream>>>(x, xb);
    k_cvt_w<<<dim3(8, 32, 10), 256, 0, stream>>>(w, wT);
    k_cvt_p<<<dim3(32, 80), 256, 0, stream>>>(p, pT);
    k_gemm1_route<<<dim3(64, 10), 512, 0, stream>>>(xb, wT, route);
    k_gemm2<<<dim3(32, 8), 512, 0, stream>>>(route, pT, out);
}